// Round 4
// baseline (234.839 us; speedup 1.0000x reference)
//
#include <hip/hip_runtime.h>
#include <hip/hip_bf16.h>

// Problem constants
#define B_    4
#define T_    4096
#define D_    1024
#define NH_   16
#define NS_   64
#define HD_   64
#define ALPHA_ 0.1f
#define M_    (B_*T_)        // 16384 rows
#define N_    (NH_*NS_)      // 1024 cols (head*slot)
#define NCH_  128            // time chunks for the suffix scan
#define CHUNK_ (T_/NCH_)     // 32

typedef __attribute__((ext_vector_type(8))) short short8v;
typedef __attribute__((ext_vector_type(4))) float f32x4;

__device__ inline unsigned short f2bf(float x) {
    unsigned u = __float_as_uint(x);
    unsigned r = u + 0x7FFF + ((u >> 16) & 1);   // RNE
    return (unsigned short)(r >> 16);
}

// ---------------------------------------------------------------------------
// Kernel 1: fold W_tok into prototypes, emit bf16:
//   P[n][m] = (1/8) * sum_{k<64} proto[s, h*64+k] * W_tok[h*64+k, m],  n = h*64+s
__global__ __launch_bounds__(256)
void k_protoproj(const float* __restrict__ proto,
                 const float* __restrict__ W,
                 unsigned short* __restrict__ Pb) {
    int n = blockIdx.x;              // 0..1023
    int h = n >> 6, s = n & 63;
    __shared__ float pl[64];
    int tid = threadIdx.x;
    if (tid < 64) pl[tid] = proto[s * D_ + h * 64 + tid];
    __syncthreads();
    #pragma unroll
    for (int j = 0; j < 4; ++j) {
        int m = j * 256 + tid;
        float acc = 0.f;
        #pragma unroll 16
        for (int k = 0; k < 64; ++k)
            acc += pl[k] * W[(h * 64 + k) * D_ + m];
        Pb[n * D_ + m] = f2bf(0.125f * acc);
    }
}

// ---------------------------------------------------------------------------
// Kernel 2: bf16 MFMA GEMM + fused softmax + per-chunk g products.
// Block tile 128x256 (M x N), 4 waves (2x2), per-wave 64x128 (4x8 frags of
// 16x16x32). Both operands reg-staged into LDA=34-padded LDS (17 is odd ->
// row->bank map bijective; all frag reads <=2-way conflict = free).
#define BM_  128
#define BN_  256
#define LDT_ 34

__global__ __launch_bounds__(256, 2)
void k_gemm_sm(const float* __restrict__ A,          // H  [M_, D_] fp32
               const unsigned short* __restrict__ Bp,// Pb [N_, D_] bf16
               float* __restrict__ C,                // w  [M_, N_] fp32 (softmaxed)
               float* __restrict__ cp) {             // [B*NH, NCH, 64]
    __shared__ short As[BM_ * LDT_];   // 8704 shorts
    __shared__ short Bs[BN_ * LDT_];   // 17408 shorts
    int tid = threadIdx.x;
    int bid = blockIdx.x;
    // XCD-bijective swizzle: 512 blocks, 8 XCDs -> 64 per XCD
    int wgid = (bid & 7) * 64 + (bid >> 3);
    int bm = wgid >> 2, bn = wgid & 3;        // 128 m-blocks, 4 n-blocks
    int m0 = bm * BM_, n0 = bn * BN_;
    int l = tid & 63, wv = tid >> 6;
    int wr = wv >> 1, wc = wv & 1;
    int lr = l & 15, lk = l >> 4;

    // A staging: 4 issues of 32 rows; thread -> row, 4-float k chunk
    int arow = tid >> 3;          // 0..31
    int akof = (tid & 7) * 4;     // floats (== shorts after cvt)
    // B staging: 4 issues of 64 rows; thread -> row, 8-short k chunk
    int brow = tid >> 2;          // 0..63
    int bkof = (tid & 3) * 8;     // shorts

    const float* Aptr = A + (size_t)(m0 + arow) * D_ + akof;
    const unsigned short* Bptr = Bp + (size_t)(n0 + brow) * D_ + bkof;

    f32x4 acc[4][8];
    #pragma unroll
    for (int i = 0; i < 4; ++i)
        #pragma unroll
        for (int j = 0; j < 8; ++j) acc[i][j] = (f32x4){0.f, 0.f, 0.f, 0.f};

    const short* afp = &As[(wr * 64 + lr) * LDT_ + lk * 8];
    const short* bfp = &Bs[(wc * 128 + lr) * LDT_ + lk * 8];

    for (int k0 = 0; k0 < D_; k0 += 32) {
        float4 a0 = *(const float4*)(Aptr + k0);
        float4 a1 = *(const float4*)(Aptr + (size_t)32 * D_ + k0);
        float4 a2 = *(const float4*)(Aptr + (size_t)64 * D_ + k0);
        float4 a3 = *(const float4*)(Aptr + (size_t)96 * D_ + k0);
        short8v b0 = *(const short8v*)(Bptr + k0);
        short8v b1 = *(const short8v*)(Bptr + (size_t)64  * D_ + k0);
        short8v b2 = *(const short8v*)(Bptr + (size_t)128 * D_ + k0);
        short8v b3 = *(const short8v*)(Bptr + (size_t)192 * D_ + k0);
        __syncthreads();   // previous tile's MFMA reads complete
        {
            __hip_bfloat162 q0 = __float22bfloat162_rn(make_float2(a0.x, a0.y));
            __hip_bfloat162 q1 = __float22bfloat162_rn(make_float2(a0.z, a0.w));
            __hip_bfloat162 q2 = __float22bfloat162_rn(make_float2(a1.x, a1.y));
            __hip_bfloat162 q3 = __float22bfloat162_rn(make_float2(a1.z, a1.w));
            __hip_bfloat162 q4 = __float22bfloat162_rn(make_float2(a2.x, a2.y));
            __hip_bfloat162 q5 = __float22bfloat162_rn(make_float2(a2.z, a2.w));
            __hip_bfloat162 q6 = __float22bfloat162_rn(make_float2(a3.x, a3.y));
            __hip_bfloat162 q7 = __float22bfloat162_rn(make_float2(a3.z, a3.w));
            *(uint2*)&As[(arow +  0) * LDT_ + akof] = (uint2){*(unsigned*)&q0, *(unsigned*)&q1};
            *(uint2*)&As[(arow + 32) * LDT_ + akof] = (uint2){*(unsigned*)&q2, *(unsigned*)&q3};
            *(uint2*)&As[(arow + 64) * LDT_ + akof] = (uint2){*(unsigned*)&q4, *(unsigned*)&q5};
            *(uint2*)&As[(arow + 96) * LDT_ + akof] = (uint2){*(unsigned*)&q6, *(unsigned*)&q7};
        }
        *(short8v*)&Bs[(brow +   0) * LDT_ + bkof] = b0;
        *(short8v*)&Bs[(brow +  64) * LDT_ + bkof] = b1;
        *(short8v*)&Bs[(brow + 128) * LDT_ + bkof] = b2;
        *(short8v*)&Bs[(brow + 192) * LDT_ + bkof] = b3;
        __syncthreads();   // staging visible
        short8v af[4], bf[8];
        #pragma unroll
        for (int m = 0; m < 4; ++m)
            af[m] = *(const short8v*)(afp + m * 16 * LDT_);
        #pragma unroll
        for (int n = 0; n < 8; ++n)
            bf[n] = *(const short8v*)(bfp + n * 16 * LDT_);
        #pragma unroll
        for (int m = 0; m < 4; ++m)
            #pragma unroll
            for (int n = 0; n < 8; ++n)
                acc[m][n] = __builtin_amdgcn_mfma_f32_16x16x32_bf16(
                    af[m], bf[n], acc[m][n], 0, 0, 0);
    }

    // ---- fused epilogue ----
    // acc[m][n][j]: row = m0 + wr*64 + m*16 + lk*4 + j
    //              col = n0 + wc*128 + n*16 + lr   (head = col/64, 2 heads/wave)
    float pch[2][8];   // [chunk pair (m<2 / m>=2)][n-frag]
    #pragma unroll
    for (int c2 = 0; c2 < 2; ++c2)
        #pragma unroll
        for (int n = 0; n < 8; ++n) pch[c2][n] = 1.f;

    #pragma unroll
    for (int hh = 0; hh < 2; ++hh) {
        #pragma unroll
        for (int m = 0; m < 4; ++m) {
            #pragma unroll
            for (int j = 0; j < 4; ++j) {
                float v0 = acc[m][hh*4+0][j], v1 = acc[m][hh*4+1][j];
                float v2 = acc[m][hh*4+2][j], v3 = acc[m][hh*4+3][j];
                float mx = fmaxf(fmaxf(v0, v1), fmaxf(v2, v3));
                #pragma unroll
                for (int off = 1; off <= 8; off <<= 1)
                    mx = fmaxf(mx, __shfl_xor(mx, off));
                float e0 = __expf(v0 - mx), e1 = __expf(v1 - mx);
                float e2 = __expf(v2 - mx), e3 = __expf(v3 - mx);
                float sm = e0 + e1 + e2 + e3;
                #pragma unroll
                for (int off = 1; off <= 8; off <<= 1)
                    sm += __shfl_xor(sm, off);
                float inv = 1.f / sm;
                float w0 = e0*inv, w1 = e1*inv, w2 = e2*inv, w3 = e3*inv;
                acc[m][hh*4+0][j] = w0; acc[m][hh*4+1][j] = w1;
                acc[m][hh*4+2][j] = w2; acc[m][hh*4+3][j] = w3;
                int c2 = m >> 1;
                pch[c2][hh*4+0] *= 1.f - ALPHA_ * w0;
                pch[c2][hh*4+1] *= 1.f - ALPHA_ * w1;
                pch[c2][hh*4+2] *= 1.f - ALPHA_ * w2;
                pch[c2][hh*4+3] *= 1.f - ALPHA_ * w3;
            }
        }
    }
    // combine the 4 lk groups (rows interleave across lanes 16 apart)
    #pragma unroll
    for (int c2 = 0; c2 < 2; ++c2)
        #pragma unroll
        for (int n = 0; n < 8; ++n) {
            pch[c2][n] *= __shfl_xor(pch[c2][n], 16);
            pch[c2][n] *= __shfl_xor(pch[c2][n], 32);
        }
    {
        int b = m0 >> 12;
        int clb = ((m0 & (T_ - 1)) >> 5) + wr * 2;
        if (lk == 0) {
            #pragma unroll
            for (int hh = 0; hh < 2; ++hh) {
                int h = bn * 4 + wc * 2 + hh;
                int gwb = (b * NH_ + h) * NCH_;
                #pragma unroll
                for (int c2 = 0; c2 < 2; ++c2)
                    #pragma unroll
                    for (int n = 0; n < 4; ++n)
                        cp[(gwb + clb + c2) * 64 + n * 16 + lr] = pch[c2][hh*4+n];
            }
        }
    }
    // store softmaxed w
    int crow = m0 + wr * 64 + lk * 4;
    int ccol = n0 + wc * 128 + lr;
    #pragma unroll
    for (int m = 0; m < 4; ++m)
        #pragma unroll
        for (int n = 0; n < 8; ++n)
            #pragma unroll
            for (int j = 0; j < 4; ++j)
                C[(size_t)(crow + m * 16 + j) * N_ + ccol + n * 16] = acc[m][n][j];
}

// ---------------------------------------------------------------------------
// Kernel 3: cross-chunk EXCLUSIVE suffix product per (b,h); thread = slot.
__global__ __launch_bounds__(64)
void k_chunk_scan(const float* __restrict__ cp, float* __restrict__ csuf) {
    int bh = blockIdx.x;     // 0..63
    int s  = threadIdx.x;    // 0..63
    float suf = 1.f;
    for (int c = NCH_ - 1; c >= 0; --c) {
        int idx = (bh * NCH_ + c) * 64 + s;
        csuf[idx] = suf;
        suf *= cp[idx];
    }
}

// ---------------------------------------------------------------------------
// Kernel 4: fused weff + output accumulation.
__global__ __launch_bounds__(256)
void k_out_fused(const float* __restrict__ w,     // softmaxed
                 const float* __restrict__ H,
                 const float* __restrict__ csuf,
                 float* __restrict__ out) {
    int bx = blockIdx.x;                  // 1024
    int cf = bx & 15, h = (bx >> 4) & 15, b = bx >> 8;
    __shared__ float ws_[32][64];
    __shared__ float hs_[32][64];
    __shared__ float ppl[4][64];
    int tid = threadIdx.x;
    int lr = tid >> 3;                    // 0..31  (tile load row)
    int lc = (tid & 7) * 8;               // 0..56  (tile load col)
    int i = tid >> 4, j = tid & 15;       // outer-product thread grid
    int s = tid & 63, q = tid >> 6;       // walk: slot s, wave-uniform quarter q
    float acc[4][4] = {};
    int t0 = cf * 256;
    int gwb = (b * NH_ + h) * NCH_ + cf * 8;
    for (int it = 0; it < 8; ++it) {
        int tb = t0 + it * 32;
        int base = (b * T_ + tb + lr) * N_ + h * 64 + lc;
        float4 wv0 = *(const float4*)&w[base];
        float4 wv1 = *(const float4*)&w[base + 4];
        float4 hv0 = *(const float4*)&H[base];
        float4 hv1 = *(const float4*)&H[base + 4];
        float su = csuf[(gwb + it) * 64 + s];
        __syncthreads();                  // prior iteration's LDS reads done
        *(float4*)&ws_[lr][lc]     = wv0;
        *(float4*)&ws_[lr][lc + 4] = wv1;
        *(float4*)&hs_[lr][lc]     = hv0;
        *(float4*)&hs_[lr][lc + 4] = hv1;
        __syncthreads();                  // tiles visible
        float pp = 1.f;
        #pragma unroll
        for (int r = 0; r < 8; ++r) pp *= 1.f - ALPHA_ * ws_[q * 8 + r][s];
        ppl[q][s] = pp;
        __syncthreads();                  // ppl visible
        float suf = su;
        if (q <= 2) suf *= ppl[3][s];
        if (q <= 1) suf *= ppl[2][s];
        if (q == 0) suf *= ppl[1][s];
        #pragma unroll
        for (int r = 7; r >= 0; --r) {
            float wv = ws_[q * 8 + r][s];
            ws_[q * 8 + r][s] = ALPHA_ * wv * suf;
            suf *= 1.f - ALPHA_ * wv;
        }
        __syncthreads();                  // w_eff visible
        #pragma unroll 8
        for (int tt = 0; tt < 32; ++tt) {
            float4 a  = *(const float4*)&ws_[tt][i * 4];
            float4 bb = *(const float4*)&hs_[tt][j * 4];
            float av[4] = {a.x, a.y, a.z, a.w};
            float bv[4] = {bb.x, bb.y, bb.z, bb.w};
            #pragma unroll
            for (int ii = 0; ii < 4; ++ii)
                #pragma unroll
                for (int jj = 0; jj < 4; ++jj)
                    acc[ii][jj] += av[ii] * bv[jj];
        }
    }
    #pragma unroll
    for (int ii = 0; ii < 4; ++ii)
        #pragma unroll
        for (int jj = 0; jj < 4; ++jj)
            atomicAdd(&out[((b * NS_ + i * 4 + ii) * NH_ + h) * HD_ + j * 4 + jj],
                      acc[ii][jj]);
}

// ---------------------------------------------------------------------------
extern "C" void kernel_launch(void* const* d_in, const int* in_sizes, int n_in,
                              void* d_out, int out_size, void* d_ws, size_t ws_size,
                              hipStream_t stream) {
    const float* H     = (const float*)d_in[0];
    const float* proto = (const float*)d_in[1];
    const float* W     = (const float*)d_in[2];
    float* out = (float*)d_out;
    char*  ws  = (char*)d_ws;

    float* w            = (float*)ws;                                    // 64 MB
    unsigned short* Pb  = (unsigned short*)(ws + (size_t)M_ * N_ * 4);   // 2 MB
    float* cp   = (float*)(ws + (size_t)M_ * N_ * 4 + (size_t)N_ * D_ * 2); // 2 MB
    float* csuf = cp + (size_t)B_ * NH_ * NCH_ * 64;                     // 2 MB

    hipMemsetAsync(d_out, 0, (size_t)out_size * sizeof(float), stream);

    k_protoproj <<<N_,                256, 0, stream>>>(proto, W, Pb);
    k_gemm_sm   <<<(M_/BM_)*(N_/BN_), 256, 0, stream>>>(H, Pb, w, cp);
    k_chunk_scan<<<B_*NH_,            64,  0, stream>>>(cp, csuf);
    k_out_fused <<<B_*NH_*16,         256, 0, stream>>>(w, H, csuf, out);
}

// Round 5
// 194.052 us; speedup vs baseline: 1.2102x; 1.2102x over previous
//
#include <hip/hip_runtime.h>
#include <hip/hip_bf16.h>

// Problem constants
#define B_    4
#define T_    4096
#define D_    1024
#define NH_   16
#define NS_   64
#define HD_   64
#define ALPHA_ 0.1f
#define M_    (B_*T_)        // 16384 rows
#define N_    (NH_*NS_)      // 1024 cols (head*slot)
#define NCH_  128            // time chunks for the suffix scan
#define CHUNK_ (T_/NCH_)     // 32

typedef __attribute__((ext_vector_type(8))) short short8v;
typedef __attribute__((ext_vector_type(4))) float f32x4;
typedef _Float16 f16x8 __attribute__((ext_vector_type(8)));

__device__ inline unsigned short f2bf(float x) {
    unsigned u = __float_as_uint(x);
    unsigned r = u + 0x7FFF + ((u >> 16) & 1);   // RNE
    return (unsigned short)(r >> 16);
}

// ---------------------------------------------------------------------------
// Kernel 0: H fp32 -> bf16 (one-time pass; removes all cvt VALU from GEMM loop
// and enables global_load_lds staging of A).
__global__ __launch_bounds__(256)
void k_h2bf(const float* __restrict__ H, unsigned short* __restrict__ Hb) {
    int idx = blockIdx.x * 256 + threadIdx.x;         // unit = 8 floats
    const int stride = 2048 * 256;
    #pragma unroll
    for (int it = 0; it < 4; ++it) {
        int e = (idx + it * stride) * 8;
        float4 f0 = *(const float4*)&H[e];
        float4 f1 = *(const float4*)&H[e + 4];
        __hip_bfloat162 q0 = __float22bfloat162_rn(make_float2(f0.x, f0.y));
        __hip_bfloat162 q1 = __float22bfloat162_rn(make_float2(f0.z, f0.w));
        __hip_bfloat162 q2 = __float22bfloat162_rn(make_float2(f1.x, f1.y));
        __hip_bfloat162 q3 = __float22bfloat162_rn(make_float2(f1.z, f1.w));
        uint4 u = {*(unsigned*)&q0, *(unsigned*)&q1, *(unsigned*)&q2, *(unsigned*)&q3};
        *(uint4*)&Hb[e] = u;
    }
}

// ---------------------------------------------------------------------------
// Kernel 1: fold W_tok into prototypes, emit bf16:
//   P[n][m] = (1/8) * sum_{k<64} proto[s, h*64+k] * W_tok[h*64+k, m],  n = h*64+s
__global__ __launch_bounds__(256)
void k_protoproj(const float* __restrict__ proto,
                 const float* __restrict__ W,
                 unsigned short* __restrict__ Pb) {
    int n = blockIdx.x;              // 0..1023
    int h = n >> 6, s = n & 63;
    __shared__ float pl[64];
    int tid = threadIdx.x;
    if (tid < 64) pl[tid] = proto[s * D_ + h * 64 + tid];
    __syncthreads();
    #pragma unroll
    for (int j = 0; j < 4; ++j) {
        int m = j * 256 + tid;
        float acc = 0.f;
        #pragma unroll 16
        for (int k = 0; k < 64; ++k)
            acc += pl[k] * W[(h * 64 + k) * D_ + m];
        Pb[n * D_ + m] = f2bf(0.125f * acc);
    }
}

// ---------------------------------------------------------------------------
// Kernel 2: pure bf16 MFMA GEMM -> raw scores in f16.
// 128x128 tile, BK=32, 4 waves (2x2 of 64x64), 16x16x32 MFMA.
// BOTH operands staged via global_load_lds width 16 into linear LDS [128][32].
// No VALU in the K-loop; acc stays in AGPRs.
__global__ __launch_bounds__(256)
void k_gemm(const unsigned short* __restrict__ Ab,   // Hb [M_, D_] bf16
            const unsigned short* __restrict__ Bp,   // Pb [N_, D_] bf16
            _Float16* __restrict__ C) {              // scores [M_, N_] f16
    __shared__ unsigned short As[128 * 32];
    __shared__ unsigned short Bs[128 * 32];
    int tid = threadIdx.x;
    int bid = blockIdx.x;
    // XCD-bijective swizzle: 1024 blocks, 8 XCDs -> 128 per XCD
    int wgid = (bid & 7) * 128 + (bid >> 3);
    int bm = wgid >> 3, bn = wgid & 7;
    int m0 = bm * 128, n0 = bn * 128;
    int l = tid & 63, wv = tid >> 6;
    int wr = wv >> 1, wc = wv & 1;
    int lr = l & 15, lk = l >> 4;

    // staging: thread -> row = tid>>2 (0..63, +64 on 2nd issue), 8-short k chunk
    int srow = tid >> 2;
    int skof = (tid & 3) * 8;
    const unsigned short* Ap = Ab + (size_t)(m0 + srow) * D_ + skof;
    const unsigned short* Bq = Bp + (size_t)(n0 + srow) * D_ + skof;

    f32x4 acc[4][4];
    #pragma unroll
    for (int i = 0; i < 4; ++i)
        #pragma unroll
        for (int j = 0; j < 4; ++j) acc[i][j] = (f32x4){0.f, 0.f, 0.f, 0.f};

    const unsigned short* afp = &As[(wr * 64 + lr) * 32 + lk * 8];
    const unsigned short* bfp = &Bs[(wc * 64 + lr) * 32 + lk * 8];

    for (int k0 = 0; k0 < D_; k0 += 32) {
        __syncthreads();   // previous tile's MFMA reads complete
        __builtin_amdgcn_global_load_lds(
            (const __attribute__((address_space(1))) void*)(Ap + k0),
            (__attribute__((address_space(3))) void*)(&As[tid * 8]), 16, 0, 0);
        __builtin_amdgcn_global_load_lds(
            (const __attribute__((address_space(1))) void*)(Ap + (size_t)64 * D_ + k0),
            (__attribute__((address_space(3))) void*)(&As[tid * 8 + 64 * 32]), 16, 0, 0);
        __builtin_amdgcn_global_load_lds(
            (const __attribute__((address_space(1))) void*)(Bq + k0),
            (__attribute__((address_space(3))) void*)(&Bs[tid * 8]), 16, 0, 0);
        __builtin_amdgcn_global_load_lds(
            (const __attribute__((address_space(1))) void*)(Bq + (size_t)64 * D_ + k0),
            (__attribute__((address_space(3))) void*)(&Bs[tid * 8 + 64 * 32]), 16, 0, 0);
        __syncthreads();   // staging visible (compiler drains vmcnt at barrier)
        short8v af[4], bf[4];
        #pragma unroll
        for (int m = 0; m < 4; ++m)
            af[m] = *(const short8v*)(afp + m * 16 * 32);
        #pragma unroll
        for (int n = 0; n < 4; ++n)
            bf[n] = *(const short8v*)(bfp + n * 16 * 32);
        #pragma unroll
        for (int m = 0; m < 4; ++m)
            #pragma unroll
            for (int n = 0; n < 4; ++n)
                acc[m][n] = __builtin_amdgcn_mfma_f32_16x16x32_bf16(
                    af[m], bf[n], acc[m][n], 0, 0, 0);
    }

    // C/D layout: col = lane&15, row = (lane>>4)*4 + j
    int crow = m0 + wr * 64 + lk * 4;
    int ccol = n0 + wc * 64 + lr;
    #pragma unroll
    for (int m = 0; m < 4; ++m)
        #pragma unroll
        for (int n = 0; n < 4; ++n)
            #pragma unroll
            for (int j = 0; j < 4; ++j)
                C[(size_t)(crow + m * 16 + j) * N_ + ccol + n * 16] =
                    (_Float16)acc[m][n][j];
}

// ---------------------------------------------------------------------------
// Kernel 3: per-chunk g-products from raw f16 scores (softmax recomputed
// in-register, no max-sub: |score| < ~5 so exp is safe). Wave = one chunk.
__global__ __launch_bounds__(256)
void k_cp(const _Float16* __restrict__ S, float* __restrict__ cp) {
    int gw   = blockIdx.x * 4 + (threadIdx.x >> 6);  // (b*16+h)*NCH_ + c
    int lane = threadIdx.x & 63;
    int c = gw & (NCH_ - 1);
    int h = (gw >> 7) & 15;
    int b = gw >> 11;
    float prod = 1.f;
    int t0 = c * CHUNK_;
    for (int t = t0; t < t0 + CHUNK_; ++t) {
        int idx = (b * T_ + t) * N_ + h * 64 + lane;
        float e = __expf((float)S[idx]);
        float sm = e;
        #pragma unroll
        for (int off = 1; off <= 32; off <<= 1) sm += __shfl_xor(sm, off);
        prod *= 1.f - ALPHA_ * (e / sm);
    }
    cp[gw * 64 + lane] = prod;
}

// ---------------------------------------------------------------------------
// Kernel 4: cross-chunk EXCLUSIVE suffix product per (b,h); thread = slot.
__global__ __launch_bounds__(64)
void k_chunk_scan(const float* __restrict__ cp, float* __restrict__ csuf) {
    int bh = blockIdx.x;     // 0..63
    int s  = threadIdx.x;    // 0..63
    float suf = 1.f;
    for (int c = NCH_ - 1; c >= 0; --c) {
        int idx = (bh * NCH_ + c) * 64 + s;
        csuf[idx] = suf;
        suf *= cp[idx];
    }
}

// ---------------------------------------------------------------------------
// Kernel 5: fused softmax + weff walk + output accumulation.
// Per LDS tile (32 t x 64 s = one chunk): row-softmax (8 lanes/row, no
// max-sub), 3-phase parallel suffix walk, 64x64 outer product, atomicAdd.
__global__ __launch_bounds__(256)
void k_out_fused(const _Float16* __restrict__ S,   // raw scores
                 const float* __restrict__ H,
                 const float* __restrict__ csuf,
                 float* __restrict__ out) {
    int bx = blockIdx.x;                  // 1024
    int cf = bx & 15, h = (bx >> 4) & 15, b = bx >> 8;
    __shared__ float ws_f[32][64];
    __shared__ float hs[32][64];
    __shared__ float ppl[4][64];
    int tid = threadIdx.x;
    int lr = tid >> 3;                    // 0..31  (tile row)
    int lc = (tid & 7) * 8;               // 0..56  (tile col)
    int i = tid >> 4, j = tid & 15;       // outer-product thread grid
    int s = tid & 63, q = tid >> 6;       // walk: slot s, wave-uniform quarter q
    float acc[4][4] = {};
    int t0 = cf * 256;
    int gwb = (b * NH_ + h) * NCH_ + cf * 8;
    for (int it = 0; it < 8; ++it) {
        int tb = t0 + it * 32;
        int base = (b * T_ + tb + lr) * N_ + h * 64 + lc;
        f16x8  sv  = *(const f16x8*)(S + base);
        float4 hv0 = *(const float4*)&H[base];
        float4 hv1 = *(const float4*)&H[base + 4];
        float  su  = csuf[(gwb + it) * 64 + s];
        // exp before barrier (register-only, overlaps)
        float ex[8]; float ps = 0.f;
        #pragma unroll
        for (int k = 0; k < 8; ++k) { ex[k] = __expf((float)sv[k]); ps += ex[k]; }
        ps += __shfl_xor(ps, 1);
        ps += __shfl_xor(ps, 2);
        ps += __shfl_xor(ps, 4);
        float inv = 1.f / ps;
        __syncthreads();                  // prior iteration's LDS reads done
        {
            float4 w0 = {ex[0]*inv, ex[1]*inv, ex[2]*inv, ex[3]*inv};
            float4 w1 = {ex[4]*inv, ex[5]*inv, ex[6]*inv, ex[7]*inv};
            *(float4*)&ws_f[lr][lc]     = w0;
            *(float4*)&ws_f[lr][lc + 4] = w1;
            *(float4*)&hs[lr][lc]       = hv0;
            *(float4*)&hs[lr][lc + 4]   = hv1;
        }
        __syncthreads();                  // tiles visible
        // phase 1: per-quarter partial products of g = 1 - alpha*w
        float pp = 1.f;
        #pragma unroll
        for (int r = 0; r < 8; ++r) pp *= 1.f - ALPHA_ * ws_f[q * 8 + r][s];
        ppl[q][s] = pp;
        __syncthreads();                  // ppl visible
        // phase 2: suffix start for this quarter, then backward walk
        float suf = su;
        if (q <= 2) suf *= ppl[3][s];
        if (q <= 1) suf *= ppl[2][s];
        if (q == 0) suf *= ppl[1][s];
        #pragma unroll
        for (int r = 7; r >= 0; --r) {
            float wv = ws_f[q * 8 + r][s];
            ws_f[q * 8 + r][s] = ALPHA_ * wv * suf;
            suf *= 1.f - ALPHA_ * wv;
        }
        __syncthreads();                  // w_eff visible
        // outer product: acc[slot-quad][d-quad] over 32 t
        #pragma unroll 8
        for (int tt = 0; tt < 32; ++tt) {
            float4 a  = *(const float4*)&ws_f[tt][i * 4];
            float4 bb = *(const float4*)&hs[tt][j * 4];
            float av[4] = {a.x, a.y, a.z, a.w};
            float bv[4] = {bb.x, bb.y, bb.z, bb.w};
            #pragma unroll
            for (int ii = 0; ii < 4; ++ii)
                #pragma unroll
                for (int jj = 0; jj < 4; ++jj)
                    acc[ii][jj] += av[ii] * bv[jj];
        }
    }
    #pragma unroll
    for (int ii = 0; ii < 4; ++ii)
        #pragma unroll
        for (int jj = 0; jj < 4; ++jj)
            atomicAdd(&out[((b * NS_ + i * 4 + ii) * NH_ + h) * HD_ + j * 4 + jj],
                      acc[ii][jj]);
}

// ---------------------------------------------------------------------------
extern "C" void kernel_launch(void* const* d_in, const int* in_sizes, int n_in,
                              void* d_out, int out_size, void* d_ws, size_t ws_size,
                              hipStream_t stream) {
    const float* H     = (const float*)d_in[0];
    const float* proto = (const float*)d_in[1];
    const float* W     = (const float*)d_in[2];
    float* out = (float*)d_out;
    char*  ws  = (char*)d_ws;

    _Float16*       S    = (_Float16*)ws;                                  // 32 MB
    unsigned short* Hb   = (unsigned short*)(ws + (size_t)M_ * N_ * 2);    // 32 MB
    unsigned short* Pb   = (unsigned short*)(ws + (size_t)M_ * N_ * 2
                                                 + (size_t)M_ * D_ * 2);   // 2 MB
    float* cp   = (float*)((char*)Pb + (size_t)N_ * D_ * 2);               // 2 MB
    float* csuf = cp + (size_t)B_ * NH_ * NCH_ * 64;                       // 2 MB

    hipMemsetAsync(d_out, 0, (size_t)out_size * sizeof(float), stream);

    k_h2bf      <<<2048,              256, 0, stream>>>(H, Hb);
    k_protoproj <<<N_,                256, 0, stream>>>(proto, W, Pb);
    k_gemm      <<<(M_/128)*(N_/128), 256, 0, stream>>>(Hb, Pb, S);
    k_cp        <<<B_*NH_*NCH_/4,     256, 0, stream>>>(S, cp);
    k_chunk_scan<<<B_*NH_,            64,  0, stream>>>(cp, csuf);
    k_out_fused <<<B_*NH_*16,         256, 0, stream>>>(S, H, csuf, out);
}

// Round 6
// 140.004 us; speedup vs baseline: 1.6774x; 1.3860x over previous
//
#include <hip/hip_runtime.h>
#include <hip/hip_bf16.h>

// Problem constants
#define B_    4
#define T_    4096
#define D_    1024
#define NH_   16
#define NS_   64
#define HD_   64
#define ALPHA_ 0.1f
#define M_    (B_*T_)        // 16384 rows
#define N_    (NH_*NS_)      // 1024 cols (head*slot)
#define NCH_  128            // time chunks for the suffix scan
#define CHUNK_ (T_/NCH_)     // 32

typedef __attribute__((ext_vector_type(8))) short short8v;
typedef __attribute__((ext_vector_type(4))) float f32x4;
typedef _Float16 f16x8 __attribute__((ext_vector_type(8)));

__device__ inline unsigned short f2bf(float x) {
    unsigned u = __float_as_uint(x);
    unsigned r = u + 0x7FFF + ((u >> 16) & 1);   // RNE
    return (unsigned short)(r >> 16);
}

// ---------------------------------------------------------------------------
// Kernel 0: H fp32 -> bf16.
__global__ __launch_bounds__(256)
void k_h2bf(const float* __restrict__ H, unsigned short* __restrict__ Hb) {
    int idx = blockIdx.x * 256 + threadIdx.x;         // unit = 8 floats
    const int stride = 2048 * 256;
    #pragma unroll
    for (int it = 0; it < 4; ++it) {
        int e = (idx + it * stride) * 8;
        float4 f0 = *(const float4*)&H[e];
        float4 f1 = *(const float4*)&H[e + 4];
        __hip_bfloat162 q0 = __float22bfloat162_rn(make_float2(f0.x, f0.y));
        __hip_bfloat162 q1 = __float22bfloat162_rn(make_float2(f0.z, f0.w));
        __hip_bfloat162 q2 = __float22bfloat162_rn(make_float2(f1.x, f1.y));
        __hip_bfloat162 q3 = __float22bfloat162_rn(make_float2(f1.z, f1.w));
        uint4 u = {*(unsigned*)&q0, *(unsigned*)&q1, *(unsigned*)&q2, *(unsigned*)&q3};
        *(uint4*)&Hb[e] = u;
    }
}

// ---------------------------------------------------------------------------
// Kernel 1: fold W_tok into prototypes, emit bf16.
__global__ __launch_bounds__(256)
void k_protoproj(const float* __restrict__ proto,
                 const float* __restrict__ W,
                 unsigned short* __restrict__ Pb) {
    int n = blockIdx.x;              // 0..1023
    int h = n >> 6, s = n & 63;
    __shared__ float pl[64];
    int tid = threadIdx.x;
    if (tid < 64) pl[tid] = proto[s * D_ + h * 64 + tid];
    __syncthreads();
    #pragma unroll
    for (int j = 0; j < 4; ++j) {
        int m = j * 256 + tid;
        float acc = 0.f;
        #pragma unroll 16
        for (int k = 0; k < 64; ++k)
            acc += pl[k] * W[(h * 64 + k) * D_ + m];
        Pb[n * D_ + m] = f2bf(0.125f * acc);
    }
}

// ---------------------------------------------------------------------------
// Kernel 2: pure bf16 MFMA GEMM -> raw scores in f16 (unchanged from R5).
__global__ __launch_bounds__(256)
void k_gemm(const unsigned short* __restrict__ Ab,   // Hb [M_, D_] bf16
            const unsigned short* __restrict__ Bp,   // Pb [N_, D_] bf16
            _Float16* __restrict__ C) {              // scores [M_, N_] f16
    __shared__ unsigned short As[128 * 32];
    __shared__ unsigned short Bs[128 * 32];
    int tid = threadIdx.x;
    int bid = blockIdx.x;
    int wgid = (bid & 7) * 128 + (bid >> 3);
    int bm = wgid >> 3, bn = wgid & 7;
    int m0 = bm * 128, n0 = bn * 128;
    int l = tid & 63, wv = tid >> 6;
    int wr = wv >> 1, wc = wv & 1;
    int lr = l & 15, lk = l >> 4;

    int srow = tid >> 2;
    int skof = (tid & 3) * 8;
    const unsigned short* Ap = Ab + (size_t)(m0 + srow) * D_ + skof;
    const unsigned short* Bq = Bp + (size_t)(n0 + srow) * D_ + skof;

    f32x4 acc[4][4];
    #pragma unroll
    for (int i = 0; i < 4; ++i)
        #pragma unroll
        for (int j = 0; j < 4; ++j) acc[i][j] = (f32x4){0.f, 0.f, 0.f, 0.f};

    const unsigned short* afp = &As[(wr * 64 + lr) * 32 + lk * 8];
    const unsigned short* bfp = &Bs[(wc * 64 + lr) * 32 + lk * 8];

    for (int k0 = 0; k0 < D_; k0 += 32) {
        __syncthreads();
        __builtin_amdgcn_global_load_lds(
            (const __attribute__((address_space(1))) void*)(Ap + k0),
            (__attribute__((address_space(3))) void*)(&As[tid * 8]), 16, 0, 0);
        __builtin_amdgcn_global_load_lds(
            (const __attribute__((address_space(1))) void*)(Ap + (size_t)64 * D_ + k0),
            (__attribute__((address_space(3))) void*)(&As[tid * 8 + 64 * 32]), 16, 0, 0);
        __builtin_amdgcn_global_load_lds(
            (const __attribute__((address_space(1))) void*)(Bq + k0),
            (__attribute__((address_space(3))) void*)(&Bs[tid * 8]), 16, 0, 0);
        __builtin_amdgcn_global_load_lds(
            (const __attribute__((address_space(1))) void*)(Bq + (size_t)64 * D_ + k0),
            (__attribute__((address_space(3))) void*)(&Bs[tid * 8 + 64 * 32]), 16, 0, 0);
        __syncthreads();
        short8v af[4], bf[4];
        #pragma unroll
        for (int m = 0; m < 4; ++m)
            af[m] = *(const short8v*)(afp + m * 16 * 32);
        #pragma unroll
        for (int n = 0; n < 4; ++n)
            bf[n] = *(const short8v*)(bfp + n * 16 * 32);
        #pragma unroll
        for (int m = 0; m < 4; ++m)
            #pragma unroll
            for (int n = 0; n < 4; ++n)
                acc[m][n] = __builtin_amdgcn_mfma_f32_16x16x32_bf16(
                    af[m], bf[n], acc[m][n], 0, 0, 0);
    }

    int crow = m0 + wr * 64 + lk * 4;
    int ccol = n0 + wc * 64 + lr;
    #pragma unroll
    for (int m = 0; m < 4; ++m)
        #pragma unroll
        for (int n = 0; n < 4; ++n)
            #pragma unroll
            for (int j = 0; j < 4; ++j)
                C[(size_t)(crow + m * 16 + j) * N_ + ccol + n * 16] =
                    (_Float16)acc[m][n][j];
}

// ---------------------------------------------------------------------------
// Kernel 3: per-chunk g-products from raw f16 scores (unchanged from R5).
__global__ __launch_bounds__(256)
void k_cp(const _Float16* __restrict__ S, float* __restrict__ cp) {
    int gw   = blockIdx.x * 4 + (threadIdx.x >> 6);  // (b*16+h)*NCH_ + c
    int lane = threadIdx.x & 63;
    int c = gw & (NCH_ - 1);
    int h = (gw >> 7) & 15;
    int b = gw >> 11;
    float prod = 1.f;
    int t0 = c * CHUNK_;
    for (int t = t0; t < t0 + CHUNK_; ++t) {
        int idx = (b * T_ + t) * N_ + h * 64 + lane;
        float e = __expf((float)S[idx]);
        float sm = e;
        #pragma unroll
        for (int off = 1; off <= 32; off <<= 1) sm += __shfl_xor(sm, off);
        prod *= 1.f - ALPHA_ * (e / sm);
    }
    cp[gw * 64 + lane] = prod;
}

// ---------------------------------------------------------------------------
// Kernel 4: cross-chunk EXCLUSIVE suffix product per (b,h); thread = slot.
__global__ __launch_bounds__(64)
void k_chunk_scan(const float* __restrict__ cp, float* __restrict__ csuf) {
    int bh = blockIdx.x;     // 0..63
    int s  = threadIdx.x;    // 0..63
    float suf = 1.f;
    for (int c = NCH_ - 1; c >= 0; --c) {
        int idx = (bh * NCH_ + c) * 64 + s;
        csuf[idx] = suf;
        suf *= cp[idx];
    }
}

// ---------------------------------------------------------------------------
// Kernel 5: softmax + weff walk + MFMA output accumulation.
// Per iter (32 t x 64 s chunk): reg softmax -> ws (fp32); Hb rows -> tmp;
// conflict-free in-LDS transpose tmp -> hd [tg][d][8] f16; walk -> wt
// [q][s][8] f16; 4 MFMA/wave (16x16x32 f16): OUT[s][d] += w_eff^T x H.
__global__ __launch_bounds__(256)
void k_out_mfma(const _Float16* __restrict__ S,       // raw scores
                const unsigned short* __restrict__ Hb,// bf16 H
                const float* __restrict__ csuf,
                float* __restrict__ out) {
    int bx = blockIdx.x;                  // 1024
    int cf = bx & 15, h = (bx >> 4) & 15, b = bx >> 8;
    __shared__ float ws_[32][68];               // softmaxed w (16B-aligned rows)
    __shared__ float ppl[4][64];
    __shared__ unsigned short tmp[32][72];      // staged Hb rows (16B-aligned)
    __shared__ _Float16 wt[4 * 64 * 8];         // w_eff^T subtiled [q][s][8]
    __shared__ _Float16 hd[4 * 64 * 8];         // H^T   subtiled [tg][d][8]
    int tid = threadIdx.x;
    int lr = tid >> 3, lc = (tid & 7) * 8;      // tile-load role: row t, 8-col
    int s = tid & 63, q = tid >> 6;             // walk/transpose role
    int l = tid & 63, wv = tid >> 6;            // mfma role
    int fr = l & 15, fk = l >> 4;

    f32x4 acc[4];
    #pragma unroll
    for (int n = 0; n < 4; ++n) acc[n] = (f32x4){0.f, 0.f, 0.f, 0.f};

    int t0 = cf * 256;
    int gwb = (b * NH_ + h) * NCH_ + cf * 8;
    for (int it = 0; it < 8; ++it) {
        int tb = t0 + it * 32;
        size_t rbase = (size_t)(b * T_ + tb + lr) * N_ + h * 64 + lc;
        f16x8  sv = *(const f16x8*)(S + rbase);
        short8v hv = *(const short8v*)(Hb + rbase);
        float  su = csuf[(gwb + it) * 64 + s];
        // softmax across the 8-lane row group (no max-sub; |score| small)
        float ex[8]; float ps = 0.f;
        #pragma unroll
        for (int k = 0; k < 8; ++k) { ex[k] = __expf((float)sv[k]); ps += ex[k]; }
        ps += __shfl_xor(ps, 1);
        ps += __shfl_xor(ps, 2);
        ps += __shfl_xor(ps, 4);
        float inv = 1.f / ps;
        __syncthreads();                  // A: prior iter's LDS reads done
        {
            float4 w0 = {ex[0]*inv, ex[1]*inv, ex[2]*inv, ex[3]*inv};
            float4 w1 = {ex[4]*inv, ex[5]*inv, ex[6]*inv, ex[7]*inv};
            *(float4*)&ws_[lr][lc]     = w0;
            *(float4*)&ws_[lr][lc + 4] = w1;
            *(short8v*)&tmp[lr][lc]    = hv;
        }
        __syncthreads();                  // B: ws + tmp visible
        // ppl partial products (per quarter q, slot s)
        float pp = 1.f;
        #pragma unroll
        for (int r = 0; r < 8; ++r) pp *= 1.f - ALPHA_ * ws_[q * 8 + r][s];
        ppl[q][s] = pp;
        // transpose: thread (d=s, tq=q) gathers 8 t for its d, cvt bf16->f16
        {
            _Float16 hreg[8];
            #pragma unroll
            for (int r = 0; r < 8; ++r) {
                unsigned short ub = tmp[q * 8 + r][s];
                float f = __uint_as_float((unsigned)ub << 16);
                hreg[r] = (_Float16)f;
            }
            *(f16x8*)&hd[(q * 64 + s) * 8] = *(f16x8*)hreg;
        }
        __syncthreads();                  // C: ppl + hd visible
        // walk: exclusive suffix within chunk, emit w_eff^T as f16
        {
            float suf = su;
            if (q <= 2) suf *= ppl[3][s];
            if (q <= 1) suf *= ppl[2][s];
            if (q == 0) suf *= ppl[1][s];
            _Float16 wreg[8];
            #pragma unroll
            for (int r = 7; r >= 0; --r) {
                float wv_ = ws_[q * 8 + r][s];
                wreg[r] = (_Float16)(ALPHA_ * wv_ * suf);
                suf *= 1.f - ALPHA_ * wv_;
            }
            *(f16x8*)&wt[(q * 64 + s) * 8] = *(f16x8*)wreg;
        }
        __syncthreads();                  // D: wt visible
        // MFMA: wave wv covers s-block wv*16, all 64 d
        {
            f16x8 af = *(const f16x8*)&wt[(fk * 64 + wv * 16 + fr) * 8];
            #pragma unroll
            for (int n = 0; n < 4; ++n) {
                f16x8 bf = *(const f16x8*)&hd[(fk * 64 + n * 16 + fr) * 8];
                acc[n] = __builtin_amdgcn_mfma_f32_16x16x32_f16(
                    af, bf, acc[n], 0, 0, 0);
            }
        }
    }
    // D layout: row (s-dim) = fk*4 + j, col (d-dim) = fr
    #pragma unroll
    for (int n = 0; n < 4; ++n)
        #pragma unroll
        for (int j = 0; j < 4; ++j)
            atomicAdd(&out[((b * NS_ + wv * 16 + fk * 4 + j) * NH_ + h) * HD_
                           + n * 16 + fr],
                      acc[n][j]);
}

// ---------------------------------------------------------------------------
extern "C" void kernel_launch(void* const* d_in, const int* in_sizes, int n_in,
                              void* d_out, int out_size, void* d_ws, size_t ws_size,
                              hipStream_t stream) {
    const float* H     = (const float*)d_in[0];
    const float* proto = (const float*)d_in[1];
    const float* W     = (const float*)d_in[2];
    float* out = (float*)d_out;
    char*  ws  = (char*)d_ws;

    _Float16*       S    = (_Float16*)ws;                                  // 32 MB
    unsigned short* Hb   = (unsigned short*)(ws + (size_t)M_ * N_ * 2);    // 32 MB
    unsigned short* Pb   = (unsigned short*)(ws + (size_t)M_ * N_ * 2
                                                 + (size_t)M_ * D_ * 2);   // 2 MB
    float* cp   = (float*)((char*)Pb + (size_t)N_ * D_ * 2);               // 2 MB
    float* csuf = cp + (size_t)B_ * NH_ * NCH_ * 64;                       // 2 MB

    hipMemsetAsync(d_out, 0, (size_t)out_size * sizeof(float), stream);

    k_h2bf      <<<2048,              256, 0, stream>>>(H, Hb);
    k_protoproj <<<N_,                256, 0, stream>>>(proto, W, Pb);
    k_gemm      <<<(M_/128)*(N_/128), 256, 0, stream>>>(Hb, Pb, S);
    k_cp        <<<B_*NH_*NCH_/4,     256, 0, stream>>>(S, cp);
    k_chunk_scan<<<B_*NH_,            64,  0, stream>>>(cp, csuf);
    k_out_mfma  <<<B_*NH_*16,         256, 0, stream>>>(S, Hb, csuf, out);
}

// Round 7
// 134.699 us; speedup vs baseline: 1.7434x; 1.0394x over previous
//
#include <hip/hip_runtime.h>
#include <hip/hip_bf16.h>

// Problem constants
#define B_    4
#define T_    4096
#define D_    1024
#define NH_   16
#define NS_   64
#define HD_   64
#define ALPHA_ 0.1f
#define M_    (B_*T_)        // 16384 rows
#define N_    (NH_*NS_)      // 1024 cols (head*slot)
#define NCH_  128            // time chunks for the suffix scan
#define CHUNK_ (T_/NCH_)     // 32

typedef __attribute__((ext_vector_type(8))) short short8v;
typedef __attribute__((ext_vector_type(4))) float f32x4;
typedef _Float16 f16x8 __attribute__((ext_vector_type(8)));

__device__ inline unsigned short f2bf(float x) {
    unsigned u = __float_as_uint(x);
    unsigned r = u + 0x7FFF + ((u >> 16) & 1);   // RNE
    return (unsigned short)(r >> 16);
}

// ---------------------------------------------------------------------------
// Kernel 0: H fp32 -> bf16.
__global__ __launch_bounds__(256)
void k_h2bf(const float* __restrict__ H, unsigned short* __restrict__ Hb) {
    int idx = blockIdx.x * 256 + threadIdx.x;         // unit = 8 floats
    const int stride = 2048 * 256;
    #pragma unroll
    for (int it = 0; it < 4; ++it) {
        int e = (idx + it * stride) * 8;
        float4 f0 = *(const float4*)&H[e];
        float4 f1 = *(const float4*)&H[e + 4];
        __hip_bfloat162 q0 = __float22bfloat162_rn(make_float2(f0.x, f0.y));
        __hip_bfloat162 q1 = __float22bfloat162_rn(make_float2(f0.z, f0.w));
        __hip_bfloat162 q2 = __float22bfloat162_rn(make_float2(f1.x, f1.y));
        __hip_bfloat162 q3 = __float22bfloat162_rn(make_float2(f1.z, f1.w));
        uint4 u = {*(unsigned*)&q0, *(unsigned*)&q1, *(unsigned*)&q2, *(unsigned*)&q3};
        *(uint4*)&Hb[e] = u;
    }
}

// ---------------------------------------------------------------------------
// Kernel 1 (v2): fold W_tok into prototypes, emit bf16. Block = (head h,
// 64-col m-range): stages 64x64 slices of proto and W in LDS; W read ONCE.
//   P[h*64+s][m] = (1/8) * sum_k proto[s, h*64+k] * W[h*64+k, m]
__global__ __launch_bounds__(256)
void k_protoproj(const float* __restrict__ proto,
                 const float* __restrict__ W,
                 unsigned short* __restrict__ Pb) {
    int bid = blockIdx.x;            // 256
    int h = bid >> 4, mr = bid & 15;
    int m0 = mr * 64;
    __shared__ float pl[64][68];
    __shared__ float Wl[64][68];
    int tid = threadIdx.x;
    int rr = tid >> 2, cg = (tid & 3) * 16;
    #pragma unroll
    for (int i = 0; i < 4; ++i)
        *(float4*)&pl[rr][cg + i * 4] =
            *(const float4*)&proto[rr * D_ + h * 64 + cg + i * 4];
    #pragma unroll
    for (int i = 0; i < 4; ++i)
        *(float4*)&Wl[rr][cg + i * 4] =
            *(const float4*)&W[(h * 64 + rr) * D_ + m0 + cg + i * 4];
    __syncthreads();
    int s = tid & 63, mg = (tid >> 6) * 16;
    float acc[16] = {};
    for (int k = 0; k < 64; ++k) {
        float pv = pl[s][k];
        #pragma unroll
        for (int i = 0; i < 16; ++i) acc[i] += pv * Wl[k][mg + i];
    }
    unsigned short ob[16];
    #pragma unroll
    for (int i = 0; i < 16; ++i) ob[i] = f2bf(0.125f * acc[i]);
    unsigned short* dst = &Pb[(size_t)(h * 64 + s) * D_ + m0 + mg];
    *(uint4*)dst       = *(uint4*)&ob[0];
    *(uint4*)(dst + 8) = *(uint4*)&ob[8];
}

// ---------------------------------------------------------------------------
// Kernel 2: pure bf16 MFMA GEMM -> raw scores in f16 (unchanged from R6).
__global__ __launch_bounds__(256)
void k_gemm(const unsigned short* __restrict__ Ab,   // Hb [M_, D_] bf16
            const unsigned short* __restrict__ Bp,   // Pb [N_, D_] bf16
            _Float16* __restrict__ C) {              // scores [M_, N_] f16
    __shared__ unsigned short As[128 * 32];
    __shared__ unsigned short Bs[128 * 32];
    int tid = threadIdx.x;
    int bid = blockIdx.x;
    int wgid = (bid & 7) * 128 + (bid >> 3);
    int bm = wgid >> 3, bn = wgid & 7;
    int m0 = bm * 128, n0 = bn * 128;
    int l = tid & 63, wv = tid >> 6;
    int wr = wv >> 1, wc = wv & 1;
    int lr = l & 15, lk = l >> 4;

    int srow = tid >> 2;
    int skof = (tid & 3) * 8;
    const unsigned short* Ap = Ab + (size_t)(m0 + srow) * D_ + skof;
    const unsigned short* Bq = Bp + (size_t)(n0 + srow) * D_ + skof;

    f32x4 acc[4][4];
    #pragma unroll
    for (int i = 0; i < 4; ++i)
        #pragma unroll
        for (int j = 0; j < 4; ++j) acc[i][j] = (f32x4){0.f, 0.f, 0.f, 0.f};

    const unsigned short* afp = &As[(wr * 64 + lr) * 32 + lk * 8];
    const unsigned short* bfp = &Bs[(wc * 64 + lr) * 32 + lk * 8];

    for (int k0 = 0; k0 < D_; k0 += 32) {
        __syncthreads();
        __builtin_amdgcn_global_load_lds(
            (const __attribute__((address_space(1))) void*)(Ap + k0),
            (__attribute__((address_space(3))) void*)(&As[tid * 8]), 16, 0, 0);
        __builtin_amdgcn_global_load_lds(
            (const __attribute__((address_space(1))) void*)(Ap + (size_t)64 * D_ + k0),
            (__attribute__((address_space(3))) void*)(&As[tid * 8 + 64 * 32]), 16, 0, 0);
        __builtin_amdgcn_global_load_lds(
            (const __attribute__((address_space(1))) void*)(Bq + k0),
            (__attribute__((address_space(3))) void*)(&Bs[tid * 8]), 16, 0, 0);
        __builtin_amdgcn_global_load_lds(
            (const __attribute__((address_space(1))) void*)(Bq + (size_t)64 * D_ + k0),
            (__attribute__((address_space(3))) void*)(&Bs[tid * 8 + 64 * 32]), 16, 0, 0);
        __syncthreads();
        short8v af[4], bf[4];
        #pragma unroll
        for (int m = 0; m < 4; ++m)
            af[m] = *(const short8v*)(afp + m * 16 * 32);
        #pragma unroll
        for (int n = 0; n < 4; ++n)
            bf[n] = *(const short8v*)(bfp + n * 16 * 32);
        #pragma unroll
        for (int m = 0; m < 4; ++m)
            #pragma unroll
            for (int n = 0; n < 4; ++n)
                acc[m][n] = __builtin_amdgcn_mfma_f32_16x16x32_bf16(
                    af[m], bf[n], acc[m][n], 0, 0, 0);
    }

    int crow = m0 + wr * 64 + lk * 4;
    int ccol = n0 + wc * 64 + lr;
    #pragma unroll
    for (int m = 0; m < 4; ++m)
        #pragma unroll
        for (int n = 0; n < 4; ++n)
            #pragma unroll
            for (int j = 0; j < 4; ++j)
                C[(size_t)(crow + m * 16 + j) * N_ + ccol + n * 16] =
                    (_Float16)acc[m][n][j];
}

// ---------------------------------------------------------------------------
// Kernel 3 (v2): per-chunk g-products, vectorized. Block = (b,h,quarter);
// wave = 8 chunks. Lane reads f16x8 (8 slots); 8-lane-group softmax;
// cross-t product via shfl_xor(8,16,32). Writes cp[bh][c][64].
__global__ __launch_bounds__(256)
void k_cp(const _Float16* __restrict__ S, float* __restrict__ cp) {
    int bid = blockIdx.x;                 // 256
    int bh = bid >> 2, qt = bid & 3;
    int b = bh >> 4, h = bh & 15;
    int w = threadIdx.x >> 6, l = threadIdx.x & 63;
    int sg = (l & 7) * 8;
    for (int k = 0; k < 8; ++k) {
        int c = qt * 32 + w * 8 + k;
        int tb = c * CHUNK_;
        float pg[8] = {1.f, 1.f, 1.f, 1.f, 1.f, 1.f, 1.f, 1.f};
        #pragma unroll
        for (int i = 0; i < 4; ++i) {
            int t = tb + (l >> 3) + i * 8;
            f16x8 sv = *(const f16x8*)(S + (size_t)(b * T_ + t) * N_ + h * 64 + sg);
            float e[8]; float ps = 0.f;
            #pragma unroll
            for (int j = 0; j < 8; ++j) { e[j] = __expf((float)sv[j]); ps += e[j]; }
            ps += __shfl_xor(ps, 1);
            ps += __shfl_xor(ps, 2);
            ps += __shfl_xor(ps, 4);
            float inv = 1.f / ps;
            #pragma unroll
            for (int j = 0; j < 8; ++j) pg[j] *= 1.f - ALPHA_ * (e[j] * inv);
        }
        #pragma unroll
        for (int off = 8; off <= 32; off <<= 1)
            #pragma unroll
            for (int j = 0; j < 8; ++j) pg[j] *= __shfl_xor(pg[j], off);
        if ((l >> 3) == 0) {
            int base = (bh * NCH_ + c) * 64 + l * 8;
            *(float4*)&cp[base]     = (float4){pg[0], pg[1], pg[2], pg[3]};
            *(float4*)&cp[base + 4] = (float4){pg[4], pg[5], pg[6], pg[7]};
        }
    }
}

// ---------------------------------------------------------------------------
// Kernel 4: softmax + weff walk + MFMA output accumulation; 64-t iterations.
// Prologue: per-lane register suffix walk over cp (L2-resident, 2 MB) ->
// su[8] (one per 32-t sub-chunk) — replaces the old k_chunk_scan kernel.
// Per iter (64 t): reg softmax -> ws16; Hb rows -> tmp; in-LDS transpose ->
// hd [tg][d][8] f16; 16-row suffix walk -> wt [tg][s][8] f16; 8 MFMA/wave.
__global__ __launch_bounds__(256)
void k_out_mfma(const _Float16* __restrict__ S,       // raw scores
                const unsigned short* __restrict__ Hb,// bf16 H
                const float* __restrict__ cp,
                float* __restrict__ out) {
    int bx = blockIdx.x;                  // 1024
    int cf = bx & 15, h = (bx >> 4) & 15, b = bx >> 8;
    __shared__ _Float16 ws16[64][72];           // softmaxed w
    __shared__ unsigned short tmp[64][72];      // staged Hb rows
    __shared__ float ppl[4][64];                // per-16-row g partial products
    __shared__ _Float16 wt[8 * 64 * 8];         // w_eff^T subtiled [tg][s][8]
    __shared__ _Float16 hd[8 * 64 * 8];         // H^T    subtiled [tg][d][8]
    int tid = threadIdx.x;
    int lr0 = tid >> 3, lc = (tid & 7) * 8;     // load role: rows lr0, lr0+32
    int s = tid & 63, q = tid >> 6;             // walk/transpose role
    int fr = s & 15, fk = s >> 4, wv = q;       // mfma role

    // --- prologue: global-suffix values su[it] = prod_{c > cf*8+it} cp[c][s]
    int cbase = (b * NH_ + h) * NCH_;
    float su[8];
    {
        float P = 1.f;
        for (int c = NCH_ - 1; c >= cf * 8 + 8; --c)
            P *= cp[(cbase + c) * 64 + s];
        su[7] = P;
        #pragma unroll
        for (int it = 6; it >= 0; --it)
            su[it] = su[it + 1] * cp[(cbase + cf * 8 + it + 1) * 64 + s];
    }

    f32x4 acc[4];
    #pragma unroll
    for (int n = 0; n < 4; ++n) acc[n] = (f32x4){0.f, 0.f, 0.f, 0.f};

    for (int it = 0; it < 4; ++it) {
        int tb = cf * 256 + it * 64;
        size_t r0 = (size_t)(b * T_ + tb + lr0) * N_ + h * 64 + lc;
        size_t r1 = r0 + (size_t)32 * N_;
        f16x8  sv0 = *(const f16x8*)(S + r0);
        f16x8  sv1 = *(const f16x8*)(S + r1);
        short8v hv0 = *(const short8v*)(Hb + r0);
        short8v hv1 = *(const short8v*)(Hb + r1);
        // softmax per row (8-lane group, no max-sub; |score| small)
        _Float16 w0[8], w1[8];
        {
            float e[8]; float ps = 0.f;
            #pragma unroll
            for (int j = 0; j < 8; ++j) { e[j] = __expf((float)sv0[j]); ps += e[j]; }
            ps += __shfl_xor(ps, 1); ps += __shfl_xor(ps, 2); ps += __shfl_xor(ps, 4);
            float inv = 1.f / ps;
            #pragma unroll
            for (int j = 0; j < 8; ++j) w0[j] = (_Float16)(e[j] * inv);
        }
        {
            float e[8]; float ps = 0.f;
            #pragma unroll
            for (int j = 0; j < 8; ++j) { e[j] = __expf((float)sv1[j]); ps += e[j]; }
            ps += __shfl_xor(ps, 1); ps += __shfl_xor(ps, 2); ps += __shfl_xor(ps, 4);
            float inv = 1.f / ps;
            #pragma unroll
            for (int j = 0; j < 8; ++j) w1[j] = (_Float16)(e[j] * inv);
        }
        __syncthreads();                  // A: prior iter's LDS reads done
        *(f16x8*)&ws16[lr0][lc]      = *(f16x8*)w0;
        *(f16x8*)&ws16[lr0 + 32][lc] = *(f16x8*)w1;
        *(short8v*)&tmp[lr0][lc]      = hv0;
        *(short8v*)&tmp[lr0 + 32][lc] = hv1;
        __syncthreads();                  // B: ws16 + tmp visible
        // ppl: partial product of g over this thread's 16 rows
        {
            float pp = 1.f;
            #pragma unroll
            for (int r = 0; r < 16; ++r)
                pp *= 1.f - ALPHA_ * (float)ws16[q * 16 + r][s];
            ppl[q][s] = pp;
        }
        // transpose Hb: thread (q,s): tg = q and q+4, cvt bf16 -> f16
        #pragma unroll
        for (int x = 0; x < 2; ++x) {
            int tg = q + x * 4;
            _Float16 hreg[8];
            #pragma unroll
            for (int r = 0; r < 8; ++r) {
                unsigned short ub = tmp[tg * 8 + r][s];
                hreg[r] = (_Float16)__uint_as_float((unsigned)ub << 16);
            }
            *(f16x8*)&hd[(tg * 64 + s) * 8] = *(f16x8*)hreg;
        }
        __syncthreads();                  // C: ppl + hd visible
        // walk: rows q*16..q*16+15 backward; chunk split at q<2 | q>=2
        {
            float suf = (q >= 2) ? su[it * 2 + 1] : su[it * 2];
            if (q == 2) suf *= ppl[3][s];
            if (q == 0) suf *= ppl[1][s];
            _Float16 wr16[16];
            #pragma unroll
            for (int r = 15; r >= 0; --r) {
                float wv_ = (float)ws16[q * 16 + r][s];
                wr16[r] = (_Float16)(ALPHA_ * wv_ * suf);
                suf *= 1.f - ALPHA_ * wv_;
            }
            *(f16x8*)&wt[((2 * q)     * 64 + s) * 8] = *(f16x8*)&wr16[0];
            *(f16x8*)&wt[((2 * q + 1) * 64 + s) * 8] = *(f16x8*)&wr16[8];
        }
        __syncthreads();                  // D: wt visible
        // MFMA: wave wv -> s-block wv*16, all 64 d; K=64 = 2 k-steps
        #pragma unroll
        for (int kk = 0; kk < 2; ++kk) {
            int tg = kk * 4 + fk;
            f16x8 af = *(const f16x8*)&wt[(tg * 64 + wv * 16 + fr) * 8];
            #pragma unroll
            for (int n = 0; n < 4; ++n) {
                f16x8 bf = *(const f16x8*)&hd[(tg * 64 + n * 16 + fr) * 8];
                acc[n] = __builtin_amdgcn_mfma_f32_16x16x32_f16(
                    af, bf, acc[n], 0, 0, 0);
            }
        }
    }
    // D layout: row (s-dim) = fk*4 + j, col (d-dim) = fr
    #pragma unroll
    for (int n = 0; n < 4; ++n)
        #pragma unroll
        for (int j = 0; j < 4; ++j)
            atomicAdd(&out[((b * NS_ + wv * 16 + fk * 4 + j) * NH_ + h) * HD_
                           + n * 16 + fr],
                      acc[n][j]);
}

// ---------------------------------------------------------------------------
extern "C" void kernel_launch(void* const* d_in, const int* in_sizes, int n_in,
                              void* d_out, int out_size, void* d_ws, size_t ws_size,
                              hipStream_t stream) {
    const float* H     = (const float*)d_in[0];
    const float* proto = (const float*)d_in[1];
    const float* W     = (const float*)d_in[2];
    float* out = (float*)d_out;
    char*  ws  = (char*)d_ws;

    _Float16*       S  = (_Float16*)ws;                                  // 32 MB
    unsigned short* Hb = (unsigned short*)(ws + (size_t)M_ * N_ * 2);    // 32 MB
    unsigned short* Pb = (unsigned short*)(ws + (size_t)M_ * N_ * 2
                                              + (size_t)M_ * D_ * 2);    // 2 MB
    float* cp = (float*)((char*)Pb + (size_t)N_ * D_ * 2);               // 2 MB

    hipMemsetAsync(d_out, 0, (size_t)out_size * sizeof(float), stream);

    k_h2bf      <<<2048,              256, 0, stream>>>(H, Hb);
    k_protoproj <<<256,               256, 0, stream>>>(proto, W, Pb);
    k_gemm      <<<(M_/128)*(N_/128), 256, 0, stream>>>(Hb, Pb, S);
    k_cp        <<<256,               256, 0, stream>>>(S, cp);
    k_out_mfma  <<<B_*NH_*16,         256, 0, stream>>>(S, Hb, cp, out);
}